// Round 1
// baseline (9484.661 us; speedup 1.0000x reference)
//
#include <hip/hip_runtime.h>
#include <math.h>

#define BB 4096
#define TT 48
#define DD 32
#define HH 256
#define G3 768
#define LL 128
#define HID 256
#define EE 8
#define NHZ 48
#define NSTEP 47
#define NTEMB (2*NSTEP+1)   // 95

// ---------------- prep kernels ----------------

__global__ void transpose_k(const float* __restrict__ src, float* __restrict__ dst, int R, int C) {
    int i = blockIdx.x * 256 + threadIdx.x;
    if (i < R * C) {
        int r = i / C, c = i % C;
        dst[c * R + r] = src[i];   // dst is [C][R]
    }
}

__global__ void temb_k(const float* __restrict__ tproj_w, const float* __restrict__ tproj_b,
                       float* __restrict__ tembs) {
    int i = blockIdx.x * 64 + threadIdx.x;
    if (i >= NTEMB) return;
    float t = (float)i / (float)(2 * NSTEP);
    const float PI = 3.14159265358979323846f;
    float emb[8];
    #pragma unroll
    for (int m = 0; m < 4; ++m) {
        float pos = t * (float)(m + 1) * PI;
        emb[m]     = sinf(pos);
        emb[4 + m] = cosf(pos);
    }
    #pragma unroll
    for (int o = 0; o < 8; ++o) {
        float a = tproj_b[o];
        #pragma unroll
        for (int k = 0; k < 8; ++k) a = fmaf(tproj_w[o * 8 + k], emb[k], a);
        tembs[i * 8 + o] = a;
    }
}

// ---------------- GRU encoder (+ fused z0 projection) ----------------
// 16 batch rows per block, 256 threads. Thread j owns output dims (j, 256+j, 512+j).

__global__ __launch_bounds__(256) void gru_k(
    const float* __restrict__ Xp, const float* __restrict__ Mp,
    const float* __restrict__ w_ihT,   // [64][768]
    const float* __restrict__ w_hhT,   // [256][768]
    const float* __restrict__ b_ih, const float* __restrict__ b_hh,
    const float* __restrict__ z0_wT,   // [256][256]
    const float* __restrict__ z0_b,
    float* __restrict__ out_mean, float* __restrict__ out_lv) {

    __shared__ float h[16 * HH];     // 16KB
    __shared__ float u[16 * 64];     // 4KB
    __shared__ float obs[16];

    int tid = threadIdx.x;
    int blk = blockIdx.x;

    for (int e = tid; e < 16 * HH; e += 256) h[e] = 0.0f;

    float brz0 = b_ih[tid]       + b_hh[tid];         // r-gate bias (i+h)
    float brz1 = b_ih[256 + tid] + b_hh[256 + tid];   // z-gate bias (i+h)
    float bin_ = b_ih[512 + tid];                     // n-gate input bias
    float bhn_ = b_hh[512 + tid];                     // n-gate hidden bias
    __syncthreads();

    for (int t = TT - 1; t >= 0; --t) {
        // stage [X_t | mask_t] for 16 rows
        #pragma unroll
        for (int i = 0; i < 4; ++i) {
            int e = tid + i * 256;
            int r = e >> 6, c = e & 63;
            int base = (blk * 16 + r) * (TT * DD) + t * DD;
            u[r * 64 + c] = (c < 32) ? Xp[base + c] : Mp[base + (c - 32)];
        }
        __syncthreads();
        if (tid < 16) {
            float sm = 0.0f;
            #pragma unroll
            for (int c = 32; c < 64; ++c) sm += u[tid * 64 + c];
            obs[tid] = (sm > 0.0f) ? 1.0f : 0.0f;
        }

        float ar[16], az[16], ain[16], ahn[16];
        #pragma unroll
        for (int r = 0; r < 16; ++r) { ar[r] = brz0; az[r] = brz1; ain[r] = bin_; ahn[r] = bhn_; }

        // input contribution (k over 64)
        #pragma unroll 4
        for (int k = 0; k < 64; ++k) {
            float w0 = w_ihT[k * G3 + tid];
            float w1 = w_ihT[k * G3 + 256 + tid];
            float w2 = w_ihT[k * G3 + 512 + tid];
            #pragma unroll
            for (int r = 0; r < 16; ++r) {
                float uv = u[r * 64 + k];
                ar[r]  = fmaf(w0, uv, ar[r]);
                az[r]  = fmaf(w1, uv, az[r]);
                ain[r] = fmaf(w2, uv, ain[r]);
            }
        }
        // hidden contribution (k over 256)
        #pragma unroll 4
        for (int k = 0; k < HH; ++k) {
            float w0 = w_hhT[k * G3 + tid];
            float w1 = w_hhT[k * G3 + 256 + tid];
            float w2 = w_hhT[k * G3 + 512 + tid];
            #pragma unroll
            for (int r = 0; r < 16; ++r) {
                float hv = h[r * HH + k];
                ar[r]  = fmaf(w0, hv, ar[r]);
                az[r]  = fmaf(w1, hv, az[r]);
                ahn[r] = fmaf(w2, hv, ahn[r]);
            }
        }

        // gates -> h_new (in regs), barrier, then write h
        float hnew[16], hold[16];
        #pragma unroll
        for (int r = 0; r < 16; ++r) {
            float rg = 1.0f / (1.0f + expf(-ar[r]));
            float zg = 1.0f / (1.0f + expf(-az[r]));
            float n  = tanhf(ain[r] + rg * ahn[r]);
            float hv = h[r * HH + tid];
            hold[r] = hv;
            hnew[r] = (1.0f - zg) * n + zg * hv;
        }
        __syncthreads();
        #pragma unroll
        for (int r = 0; r < 16; ++r) {
            float o = obs[r];
            h[r * HH + tid] = o * hnew[r] + (1.0f - o) * hold[r];
        }
        __syncthreads();
    }

    // fused z0 projection: z0_out[r][tid] = sum_k h[r][k] * z0_w[tid][k] + z0_b[tid]
    float zr[16];
    #pragma unroll
    for (int r = 0; r < 16; ++r) zr[r] = z0_b[tid];
    #pragma unroll 4
    for (int k = 0; k < HH; ++k) {
        float w = z0_wT[k * 256 + tid];
        #pragma unroll
        for (int r = 0; r < 16; ++r) zr[r] = fmaf(w, h[r * HH + k], zr[r]);
    }
    int row0 = blk * 16;
    if (tid < 128) {
        #pragma unroll
        for (int r = 0; r < 16; ++r) out_mean[(row0 + r) * LL + tid] = zr[r];
    } else {
        #pragma unroll
        for (int r = 0; r < 16; ++r) out_lv[(row0 + r) * LL + (tid - 128)] = zr[r];
    }
}

// ---------------- ODE (RK4, 47 steps) + DeepHit head ----------------

__device__ __forceinline__ void ode_f(
    const float* in, float* hb, float* fo,
    const float* __restrict__ w1T, const float* __restrict__ w2T, const float* __restrict__ w3T,
    const float* temb_s, float b1j, float b2j, float b3o, int tid) {

    // phase A: h1 = tanh([z,temb] @ w1.T + b1)   -> hb[16][256]
    float acc[16];
    #pragma unroll
    for (int r = 0; r < 16; ++r) acc[r] = b1j;
    #pragma unroll 4
    for (int k = 0; k < LL; ++k) {
        float w = w1T[k * 256 + tid];
        #pragma unroll
        for (int r = 0; r < 16; ++r) acc[r] = fmaf(w, in[r * LL + k], acc[r]);
    }
    float tacc = 0.0f;
    #pragma unroll
    for (int k = 0; k < EE; ++k) tacc = fmaf(w1T[(LL + k) * 256 + tid], temb_s[k], tacc);
    #pragma unroll
    for (int r = 0; r < 16; ++r) hb[r * HID + tid] = tanhf(acc[r] + tacc);
    __syncthreads();

    // phase B: h2 = tanh(h1 @ w2.T + b2)  (regs, then overwrite hb)
    float a2[16];
    #pragma unroll
    for (int r = 0; r < 16; ++r) a2[r] = b2j;
    #pragma unroll 4
    for (int k = 0; k < HID; ++k) {
        float w = w2T[k * 256 + tid];
        #pragma unroll
        for (int r = 0; r < 16; ++r) a2[r] = fmaf(w, hb[r * HID + k], a2[r]);
    }
    __syncthreads();
    #pragma unroll
    for (int r = 0; r < 16; ++r) hb[r * HID + tid] = tanhf(a2[r]);
    __syncthreads();

    // phase C: fo = h2 @ w3.T + b3  (thread covers 8 rows at dim tid&127)
    int od = tid & 127;
    int r0 = (tid >> 7) * 8;
    float a3[8];
    #pragma unroll
    for (int rr = 0; rr < 8; ++rr) a3[rr] = b3o;
    #pragma unroll 4
    for (int k = 0; k < HID; ++k) {
        float w = w3T[k * LL + od];
        #pragma unroll
        for (int rr = 0; rr < 8; ++rr) a3[rr] = fmaf(w, hb[(r0 + rr) * HID + k], a3[rr]);
    }
    #pragma unroll
    for (int rr = 0; rr < 8; ++rr) fo[(r0 + rr) * LL + od] = a3[rr];
    __syncthreads();
}

__global__ __launch_bounds__(256) void ode_head_k(
    const float* __restrict__ zinit,
    const float* __restrict__ w1T, const float* __restrict__ w2T, const float* __restrict__ w3T,
    const float* __restrict__ b1, const float* __restrict__ b2, const float* __restrict__ b3,
    const float* __restrict__ tembs,
    const float* __restrict__ shw1g, const float* __restrict__ shb1,
    const float* __restrict__ shw2, const float* __restrict__ shb2,
    float* __restrict__ out_haz, float* __restrict__ out_surv, float* __restrict__ out_pg) {

    __shared__ float z [16 * LL];
    __shared__ float ztl[16 * LL];
    __shared__ float fo[16 * LL];
    __shared__ float ka[16 * LL];
    __shared__ float hb[16 * HID];
    __shared__ float shw1[32 * (LL + 1)];   // +1 pad: unpadded stride 128 = 16-way bank conflict
    __shared__ float temb_s[EE];
    __shared__ float cum[16];

    int tid = threadIdx.x, blk = blockIdx.x;
    int s = tid & 15;
    float b1j = b1[tid], b2j = b2[tid], b3o = b3[tid & 127];
    float w2a = shw2[s], w2b = shw2[16 + s];
    float b1a = shb1[s], b1b = shb1[16 + s];
    float b2s = shb2[0];

    #pragma unroll
    for (int i = 0; i < 8; ++i) { int e = tid + (i << 8); z[e] = zinit[blk * 2048 + e]; }
    #pragma unroll
    for (int i = 0; i < 16; ++i) {
        int e = tid + (i << 8);
        shw1[(e >> 7) * (LL + 1) + (e & 127)] = shw1g[e];
    }
    if (tid < 16) cum[tid] = 0.0f;
    __syncthreads();

    const float hh = 1.0f / 47.0f;

    for (int jout = 0; jout <= NSTEP; ++jout) {
        // ---- emit head at current z (time jout/47) ----
        {
            int r = tid >> 4;
            float aa = b1a, ab = b1b;
            #pragma unroll 4
            for (int k = 0; k < LL; ++k) {
                float zk = z[r * LL + k];
                aa = fmaf(shw1[s * (LL + 1) + k], zk, aa);
                ab = fmaf(shw1[(16 + s) * (LL + 1) + k], zk, ab);
            }
            float p = fmaxf(aa, 0.0f) * w2a + fmaxf(ab, 0.0f) * w2b;
            p += __shfl_xor(p, 1); p += __shfl_xor(p, 2);
            p += __shfl_xor(p, 4); p += __shfl_xor(p, 8);
            if (s == 0) {
                float hz = 1.0f / (1.0f + expf(-(p + b2s)));
                int row = blk * 16 + r;
                float sv = expf(cum[r]);
                out_haz [row * NHZ + jout] = hz;
                out_surv[row * NHZ + jout] = sv;
                cum[r] += logf(1.0f - hz + 1e-7f);
                if (jout == NHZ - 1) out_pg[row] = 1.0f - sv;
            }
        }
        if (jout == NSTEP) break;

        // ---- one RK4 step jout/47 -> (jout+1)/47 ----
        int st = jout;
        if (tid < 8) temb_s[tid] = tembs[(2 * st) * 8 + tid];
        __syncthreads();
        ode_f(z, hb, fo, w1T, w2T, w3T, temb_s, b1j, b2j, b3o, tid);    // k1
        #pragma unroll
        for (int i = 0; i < 8; ++i) {
            int e = tid + (i << 8); float f = fo[e];
            ka[e] = f; ztl[e] = z[e] + 0.5f * hh * f;
        }
        if (tid < 8) temb_s[tid] = tembs[(2 * st + 1) * 8 + tid];
        __syncthreads();
        ode_f(ztl, hb, fo, w1T, w2T, w3T, temb_s, b1j, b2j, b3o, tid);  // k2
        #pragma unroll
        for (int i = 0; i < 8; ++i) {
            int e = tid + (i << 8); float f = fo[e];
            ka[e] += 2.0f * f; ztl[e] = z[e] + 0.5f * hh * f;
        }
        __syncthreads();
        ode_f(ztl, hb, fo, w1T, w2T, w3T, temb_s, b1j, b2j, b3o, tid);  // k3
        #pragma unroll
        for (int i = 0; i < 8; ++i) {
            int e = tid + (i << 8); float f = fo[e];
            ka[e] += 2.0f * f; ztl[e] = z[e] + hh * f;
        }
        if (tid < 8) temb_s[tid] = tembs[(2 * st + 2) * 8 + tid];
        __syncthreads();
        ode_f(ztl, hb, fo, w1T, w2T, w3T, temb_s, b1j, b2j, b3o, tid);  // k4
        #pragma unroll
        for (int i = 0; i < 8; ++i) {
            int e = tid + (i << 8);
            z[e] += (hh / 6.0f) * (ka[e] + fo[e]);
        }
        __syncthreads();
    }
}

// ---------------- launch ----------------

extern "C" void kernel_launch(void* const* d_in, const int* in_sizes, int n_in,
                              void* d_out, int out_size, void* d_ws, size_t ws_size,
                              hipStream_t stream) {
    const float* X        = (const float*)d_in[0];
    const float* Mask     = (const float*)d_in[1];
    const float* gru_w_ih = (const float*)d_in[2];
    const float* gru_w_hh = (const float*)d_in[3];
    const float* gru_b_ih = (const float*)d_in[4];
    const float* gru_b_hh = (const float*)d_in[5];
    const float* z0_w     = (const float*)d_in[6];
    const float* z0_b     = (const float*)d_in[7];
    const float* tproj_w  = (const float*)d_in[8];
    const float* tproj_b  = (const float*)d_in[9];
    const float* ode_w1   = (const float*)d_in[10];
    const float* ode_b1   = (const float*)d_in[11];
    const float* ode_w2   = (const float*)d_in[12];
    const float* ode_b2   = (const float*)d_in[13];
    const float* ode_w3   = (const float*)d_in[14];
    const float* ode_b3   = (const float*)d_in[15];
    const float* sh_w1    = (const float*)d_in[16];
    const float* sh_b1    = (const float*)d_in[17];
    const float* sh_w2    = (const float*)d_in[18];
    const float* sh_b2    = (const float*)d_in[19];

    float* ws    = (float*)d_ws;
    float* w_ihT = ws;                    // 64*768    = 49152
    float* w_hhT = w_ihT + 49152;         // 256*768   = 196608
    float* z0_wT = w_hhT + 196608;        // 256*256   = 65536
    float* w1T   = z0_wT + 65536;         // 136*256   = 34816
    float* w2T   = w1T   + 34816;         // 256*256   = 65536
    float* w3T   = w2T   + 65536;         // 256*128   = 32768
    float* tembs = w3T   + 32768;         // 95*8      = 760

    float* out      = (float*)d_out;
    float* out_haz  = out;                              // 4096*48
    float* out_surv = out + 196608;                     // 4096*48
    float* out_mean = out + 393216;                     // 4096*128
    float* out_lv   = out + 917504;                     // 4096*128
    float* out_pg   = out + 1441792;                    // 4096

    transpose_k<<<(768*64  + 255) / 256, 256, 0, stream>>>(gru_w_ih, w_ihT, 768, 64);
    transpose_k<<<(768*256 + 255) / 256, 256, 0, stream>>>(gru_w_hh, w_hhT, 768, 256);
    transpose_k<<<(256*256 + 255) / 256, 256, 0, stream>>>(z0_w,     z0_wT, 256, 256);
    transpose_k<<<(256*136 + 255) / 256, 256, 0, stream>>>(ode_w1,   w1T,   256, 136);
    transpose_k<<<(256*256 + 255) / 256, 256, 0, stream>>>(ode_w2,   w2T,   256, 256);
    transpose_k<<<(128*256 + 255) / 256, 256, 0, stream>>>(ode_w3,   w3T,   128, 256);
    temb_k<<<2, 64, 0, stream>>>(tproj_w, tproj_b, tembs);

    gru_k<<<BB / 16, 256, 0, stream>>>(X, Mask, w_ihT, w_hhT, gru_b_ih, gru_b_hh,
                                       z0_wT, z0_b, out_mean, out_lv);

    // ODE initial state = z0_mean, read directly from d_out (written above, same stream)
    ode_head_k<<<BB / 16, 256, 0, stream>>>(out_mean, w1T, w2T, w3T,
                                            ode_b1, ode_b2, ode_b3, tembs,
                                            sh_w1, sh_b1, sh_w2, sh_b2,
                                            out_haz, out_surv, out_pg);
}